// Round 1
// baseline (845.597 us; speedup 1.0000x reference)
//
#include <hip/hip_runtime.h>

#define NEG_SLOPE 0.2f

// ---------------------------------------------------------------- CSR build
__global__ void zero_int_kernel(int* __restrict__ p, int n) {
  int i = blockIdx.x * blockDim.x + threadIdx.x;
  if (i < n) p[i] = 0;
}

__global__ void count_kernel(const int* __restrict__ ei, int E, int N,
                             int* __restrict__ cnt) {
  int e = blockIdx.x * blockDim.x + threadIdx.x;
  int tot = E + N;
  if (e >= tot) return;
  int dst = (e < E) ? ei[E + e] : (e - E);
  atomicAdd(&cnt[dst], 1);
}

__global__ __launch_bounds__(1024) void scan_kernel(const int* __restrict__ cnt,
                                                    int* __restrict__ row_ptr,
                                                    int* __restrict__ cursor,
                                                    int N) {
  __shared__ int sdata[1024];
  __shared__ int s_running;
  if (threadIdx.x == 0) s_running = 0;
  __syncthreads();
  int nch = (N + 1023) >> 10;
  for (int c = 0; c < nch; ++c) {
    int idx = (c << 10) + threadIdx.x;
    int v = (idx < N) ? cnt[idx] : 0;
    sdata[threadIdx.x] = v;
    __syncthreads();
    // Hillis-Steele inclusive scan over 1024
    for (int off = 1; off < 1024; off <<= 1) {
      int t = (threadIdx.x >= off) ? sdata[threadIdx.x - off] : 0;
      __syncthreads();
      sdata[threadIdx.x] += t;
      __syncthreads();
    }
    int excl = sdata[threadIdx.x] - v;
    if (idx < N) {
      int rp = s_running + excl;   // read s_running BEFORE the update barrier
      row_ptr[idx] = rp;
      cursor[idx] = rp;
    }
    __syncthreads();
    if (threadIdx.x == 1023) s_running += sdata[1023];
    __syncthreads();
  }
  if (threadIdx.x == 0) row_ptr[N] = s_running;
}

__global__ void fill_kernel(const int* __restrict__ ei, int E, int N,
                            int* __restrict__ cursor, int* __restrict__ col_src) {
  int e = blockIdx.x * blockDim.x + threadIdx.x;
  int tot = E + N;
  if (e >= tot) return;
  int src, dst;
  if (e < E) { src = ei[e]; dst = ei[E + e]; } else { src = e - E; dst = e - E; }
  int pos = atomicAdd(&cursor[dst], 1);
  col_src[pos] = src;
}

// ---------------------------------------------------------------- SGEMM fp32
// Y[M,N] = X[M,K] @ W[K,N].  BM=BN=64, BK=16, 256 threads, 4x4 microtile.
__global__ __launch_bounds__(256) void sgemm_kernel(const float* __restrict__ X,
                                                    const float* __restrict__ W,
                                                    float* __restrict__ Y,
                                                    int M, int N, int K) {
  constexpr int BM = 64, BN = 64, BK = 16, TM = 4, TN = 4;
  __shared__ float As[BK][BM + 1];   // +1 pad: kills 16-way write conflict
  __shared__ float Bs[BK][BN];
  int tid = threadIdx.x;
  int block_row = blockIdx.y * BM;
  int block_col = blockIdx.x * BN;
  int trow = tid / 16;
  int tcol = tid % 16;
  float acc[TM][TN] = {};
  for (int k0 = 0; k0 < K; k0 += BK) {
#pragma unroll
    for (int i = 0; i < (BM * BK) / 256; ++i) {       // 4 elems/thread
      int li = tid + i * 256;
      int m = li >> 4;
      int kk = li & 15;
      int gm = block_row + m;
      As[kk][m] = (gm < M) ? X[(size_t)gm * K + (k0 + kk)] : 0.f;
    }
#pragma unroll
    for (int i = 0; i < (BK * BN) / 256; ++i) {
      int li = tid + i * 256;
      int kk = li >> 6;
      int n = li & 63;
      Bs[kk][n] = W[(size_t)(k0 + kk) * N + block_col + n];
    }
    __syncthreads();
#pragma unroll
    for (int kk = 0; kk < BK; ++kk) {
      float ar[TM], br[TN];
#pragma unroll
      for (int i = 0; i < TM; ++i) ar[i] = As[kk][trow * TM + i];
#pragma unroll
      for (int j = 0; j < TN; ++j) br[j] = Bs[kk][tcol * TN + j];
#pragma unroll
      for (int i = 0; i < TM; ++i)
#pragma unroll
        for (int j = 0; j < TN; ++j) acc[i][j] += ar[i] * br[j];
    }
    __syncthreads();
  }
#pragma unroll
  for (int i = 0; i < TM; ++i) {
    int gm = block_row + trow * TM + i;
    if (gm >= M) continue;
#pragma unroll
    for (int j = 0; j < TN; ++j)
      Y[(size_t)gm * N + block_col + tcol * TN + j] = acc[i][j];
  }
}

// ------------------------------------------------- per-node alpha_s/alpha_d
// one wave (64 lanes) per node; h row = H*C floats, a_s/a_d = [H,C] flat
template <int H, int C>
__global__ void alpha_kernel(const float* __restrict__ h,
                             const float* __restrict__ a_s,
                             const float* __restrict__ a_d,
                             float* __restrict__ out_s,
                             float* __restrict__ out_d, int N) {
  constexpr int HC = H * C;
  constexpr int PER = HC / 64;       // floats per lane
  constexpr int SEG = C / PER;       // lanes per head
  int lane = threadIdx.x & 63;
  int node = (blockIdx.x * blockDim.x + threadIdx.x) >> 6;
  if (node >= N) return;
  int cbase = lane * PER;
  const float* row = h + (size_t)node * HC + cbase;
  float ss, dd;
  if constexpr (PER == 4) {
    float4 v = *(const float4*)row;
    float4 s4 = *(const float4*)(a_s + cbase);
    float4 d4 = *(const float4*)(a_d + cbase);
    ss = v.x * s4.x + v.y * s4.y + v.z * s4.z + v.w * s4.w;
    dd = v.x * d4.x + v.y * d4.y + v.z * d4.z + v.w * d4.w;
  } else {
    float v = row[0];
    ss = v * a_s[cbase];
    dd = v * a_d[cbase];
  }
#pragma unroll
  for (int off = SEG >> 1; off >= 1; off >>= 1) {
    ss += __shfl_xor(ss, off, 64);
    dd += __shfl_xor(dd, off, 64);
  }
  if ((lane % SEG) == 0) {
    int head = lane / SEG;
    out_s[(size_t)node * H + head] = ss;
    out_d[(size_t)node * H + head] = dd;
  }
}

// ------------------------------- segment softmax + mean-aggregate + bias(+relu)
// one wave per dst node, CSR gather over incoming edges
template <int H, int C, bool RELU>
__global__ void aggregate_kernel(const float* __restrict__ h,
                                 const float* __restrict__ as_,
                                 const float* __restrict__ ad_,
                                 const int* __restrict__ row_ptr,
                                 const int* __restrict__ col_src,
                                 const float* __restrict__ bias,
                                 float* __restrict__ out, int N) {
  constexpr int HC = H * C;
  constexpr int PER = HC / 64;
  int lane = threadIdx.x & 63;
  int node = (blockIdx.x * blockDim.x + threadIdx.x) >> 6;
  if (node >= N) return;
  int beg = row_ptr[node], end = row_ptr[node + 1];
  int deg = end - beg;
  float adv[H];
#pragma unroll
  for (int hh = 0; hh < H; ++hh) adv[hh] = ad_[(size_t)node * H + hh];

  // pass 1: per-head max over incoming edges
  float mx[H];
#pragma unroll
  for (int hh = 0; hh < H; ++hh) mx[hh] = -1e30f;
  for (int i = beg + lane; i < end; i += 64) {
    int s = col_src[i];
#pragma unroll
    for (int hh = 0; hh < H; ++hh) {
      float e = as_[(size_t)s * H + hh] + adv[hh];
      e = (e > 0.f) ? e : NEG_SLOPE * e;
      mx[hh] = fmaxf(mx[hh], e);
    }
  }
#pragma unroll
  for (int hh = 0; hh < H; ++hh)
#pragma unroll
    for (int off = 32; off >= 1; off >>= 1)
      mx[hh] = fmaxf(mx[hh], __shfl_xor(mx[hh], off, 64));

  // pass 2: per-head denom
  float dn[H];
#pragma unroll
  for (int hh = 0; hh < H; ++hh) dn[hh] = 0.f;
  for (int i = beg + lane; i < end; i += 64) {
    int s = col_src[i];
#pragma unroll
    for (int hh = 0; hh < H; ++hh) {
      float e = as_[(size_t)s * H + hh] + adv[hh];
      e = (e > 0.f) ? e : NEG_SLOPE * e;
      dn[hh] += expf(e - mx[hh]);
    }
  }
#pragma unroll
  for (int hh = 0; hh < H; ++hh)
#pragma unroll
    for (int off = 32; off >= 1; off >>= 1)
      dn[hh] += __shfl_xor(dn[hh], off, 64);

  // pass 3: weighted gather of h[src] rows (whole wave per edge)
  int myhead = (lane * PER) / C;
  float facc[PER] = {};
  float adm = adv[myhead];
  for (int i = beg; i < end; ++i) {
    int s = col_src[i];
    float e = as_[(size_t)s * H + myhead] + adm;
    e = (e > 0.f) ? e : NEG_SLOPE * e;
    float w = expf(e - mx[myhead]) / dn[myhead];
    const float* hrow = h + (size_t)s * HC + lane * PER;
    if constexpr (PER == 4) {
      float4 v = *(const float4*)hrow;
      facc[0] += v.x * w; facc[1] += v.y * w;
      facc[2] += v.z * w; facc[3] += v.w * w;
    } else {
      facc[0] += hrow[0] * w;
    }
  }
  float inv_deg = 1.0f / (float)deg;
  float* orow = out + (size_t)node * HC + lane * PER;
#pragma unroll
  for (int p = 0; p < PER; ++p) {
    float v = facc[p] * inv_deg + bias[lane * PER + p];
    if (RELU) v = fmaxf(v, 0.f);
    orow[p] = v;
  }
}

// ---------------------------------------------------------------- launcher
extern "C" void kernel_launch(void* const* d_in, const int* in_sizes, int n_in,
                              void* d_out, int out_size, void* d_ws, size_t ws_size,
                              hipStream_t stream) {
  const float* x   = (const float*)d_in[0];
  const int*   ei  = (const int*)d_in[1];
  const float* W0  = (const float*)d_in[2];
  const float* a0s = (const float*)d_in[3];
  const float* a0d = (const float*)d_in[4];
  const float* b0  = (const float*)d_in[5];
  const float* W1  = (const float*)d_in[6];
  const float* a1s = (const float*)d_in[7];
  const float* a1d = (const float*)d_in[8];
  const float* b1  = (const float*)d_in[9];
  const float* W2  = (const float*)d_in[10];
  const float* a2s = (const float*)d_in[11];
  const float* a2d = (const float*)d_in[12];
  const float* b2  = (const float*)d_in[13];

  const int IN = 256;
  const int N = in_sizes[0] / IN;       // 50000
  const int E = in_sizes[1] / 2;        // 600000
  const int Etot = E + N;

  char* ws = (char*)d_ws;
  size_t off = 0;
  auto alloc = [&](size_t bytes) {
    void* p = ws + off;
    off += (bytes + 255) & ~(size_t)255;
    return p;
  };
  float* A       = (float*)alloc((size_t)N * 256 * 4);  // GEMM output / h_lin
  float* Bbuf    = (float*)alloc((size_t)N * 256 * 4);  // aggregated output
  float* as_buf  = (float*)alloc((size_t)N * 4 * 4);
  float* ad_buf  = (float*)alloc((size_t)N * 4 * 4);
  int*   row_ptr = (int*)alloc((size_t)(N + 1) * 4);
  int*   cursor  = (int*)alloc((size_t)N * 4);
  int*   cnt     = (int*)alloc((size_t)N * 4);
  int*   col_src = (int*)alloc((size_t)Etot * 4);

  // ---- CSR build (every call; ws is re-poisoned) ----
  zero_int_kernel<<<(N + 255) / 256, 256, 0, stream>>>(cnt, N);
  count_kernel<<<(Etot + 255) / 256, 256, 0, stream>>>(ei, E, N, cnt);
  scan_kernel<<<1, 1024, 0, stream>>>(cnt, row_ptr, cursor, N);
  fill_kernel<<<(Etot + 255) / 256, 256, 0, stream>>>(ei, E, N, cursor, col_src);

  dim3 g0(256 / 64, (N + 63) / 64);
  dim3 g2(64 / 64, (N + 63) / 64);
  int node_blocks = (N + 3) / 4;   // 4 waves/block, 1 wave/node

  // ---- layer 0: IN=256 -> 4 heads x 64, relu ----
  sgemm_kernel<<<g0, 256, 0, stream>>>(x, W0, A, N, 256, 256);
  alpha_kernel<4, 64><<<node_blocks, 256, 0, stream>>>(A, a0s, a0d, as_buf, ad_buf, N);
  aggregate_kernel<4, 64, true><<<node_blocks, 256, 0, stream>>>(
      A, as_buf, ad_buf, row_ptr, col_src, b0, Bbuf, N);

  // ---- layer 1: 256 -> 4 heads x 64, relu ----
  sgemm_kernel<<<g0, 256, 0, stream>>>(Bbuf, W1, A, N, 256, 256);
  alpha_kernel<4, 64><<<node_blocks, 256, 0, stream>>>(A, a1s, a1d, as_buf, ad_buf, N);
  aggregate_kernel<4, 64, true><<<node_blocks, 256, 0, stream>>>(
      A, as_buf, ad_buf, row_ptr, col_src, b1, Bbuf, N);

  // ---- layer 2: 256 -> 1 head x 64, no relu ----
  sgemm_kernel<<<g2, 256, 0, stream>>>(Bbuf, W2, A, N, 64, 256);
  alpha_kernel<1, 64><<<node_blocks, 256, 0, stream>>>(A, a2s, a2d, as_buf, ad_buf, N);
  aggregate_kernel<1, 64, false><<<node_blocks, 256, 0, stream>>>(
      A, as_buf, ad_buf, row_ptr, col_src, b2, (float*)d_out, N);
}

// Round 2
// 781.713 us; speedup vs baseline: 1.0817x; 1.0817x over previous
//
#include <hip/hip_runtime.h>

#define NEG_SLOPE 0.2f

// ---------------------------------------------------------------- CSR build
__global__ void zero_int_kernel(int* __restrict__ p, int n) {
  int i = blockIdx.x * blockDim.x + threadIdx.x;
  if (i < n) p[i] = 0;
}

__global__ void count_kernel(const int* __restrict__ ei, int E, int N,
                             int* __restrict__ cnt) {
  int e = blockIdx.x * blockDim.x + threadIdx.x;
  int tot = E + N;
  if (e >= tot) return;
  int dst = (e < E) ? ei[E + e] : (e - E);
  atomicAdd(&cnt[dst], 1);
}

// 1024 threads, one block. Per-thread serial chunk + shuffle block-scan.
__global__ __launch_bounds__(1024) void scan_kernel(const int* __restrict__ cnt,
                                                    int* __restrict__ row_ptr,
                                                    int* __restrict__ cursor,
                                                    int N) {
  int t = threadIdx.x;
  int CH = (N + 1023) >> 10;
  int b = t * CH; if (b > N) b = N;
  int e = b + CH; if (e > N) e = N;
  int sum = 0;
  for (int i = b; i < e; ++i) sum += cnt[i];
  int lane = t & 63, wid = t >> 6;
  // wave inclusive scan
  int v = sum;
#pragma unroll
  for (int off = 1; off < 64; off <<= 1) {
    int u = __shfl_up(v, off, 64);
    if (lane >= off) v += u;
  }
  __shared__ int wsum[16];
  __shared__ int wpre[16];
  if (lane == 63) wsum[wid] = v;
  __syncthreads();
  if (t < 16) {
    int wv = wsum[t];
#pragma unroll
    for (int off = 1; off < 16; off <<= 1) {
      int u = __shfl_up(wv, off, 16);
      if (t >= off) wv += u;
    }
    wpre[t] = wv - wsum[t];  // exclusive across waves
  }
  __syncthreads();
  int run = wpre[wid] + (v - sum);  // global exclusive prefix for this thread
  for (int i = b; i < e; ++i) {
    int c = cnt[i];
    row_ptr[i] = run;
    cursor[i] = run;
    run += c;
  }
  if (t == 1023) row_ptr[N] = run;
}

__global__ void fill_kernel(const int* __restrict__ ei, int E, int N,
                            int* __restrict__ cursor, int* __restrict__ col_src) {
  int e = blockIdx.x * blockDim.x + threadIdx.x;
  int tot = E + N;
  if (e >= tot) return;
  int src, dst;
  if (e < E) { src = ei[e]; dst = ei[E + e]; } else { src = e - E; dst = e - E; }
  int pos = atomicAdd(&cursor[dst], 1);
  col_src[pos] = src;
}

// ---------------------------------------------------------------- SGEMM fp32
// Y[M,N] = X[M,K] @ W[K,N].  256 threads, BK=16.
// BM=128 always. BN=128: 8x8 microtile split into 4+4 halves. BN=64: 8x4.
template <int BM, int BN>
__global__ __launch_bounds__(256) void sgemm_kernel(const float* __restrict__ X,
                                                    const float* __restrict__ W,
                                                    float* __restrict__ Y,
                                                    int M, int N, int K) {
  constexpr int BK = 16;
  constexpr int LDA = BM + 4;            // pad: transpose-writes land 2-way (free)
  constexpr int HM = BM / 2;             // 64
  constexpr int JH = (BN == 128) ? 2 : 1;
  constexpr int HN = BN / 2;             // 64 or 32 (HN used only when JH==2)
  __shared__ float As[BK][LDA];
  __shared__ float Bs[BK][BN];
  int tid = threadIdx.x;
  int br = blockIdx.y * BM, bc = blockIdx.x * BN;
  int trow = tid >> 4, tcol = tid & 15;  // 16x16 thread grid
  float acc[2][JH][4][4] = {};
  constexpr int nA4 = BM * BK / 1024;    // float4 loads per thread for A
  constexpr int nB4 = BK * BN / 1024;
  for (int k0 = 0; k0 < K; k0 += BK) {
#pragma unroll
    for (int i = 0; i < nA4; ++i) {
      int f = tid + i * 256;             // float4 id; 4 per row (BK=16)
      int row = f >> 2;
      int kq = (f & 3) * 4;
      int gm = br + row;
      float4 v = make_float4(0.f, 0.f, 0.f, 0.f);
      if (gm < M) v = *(const float4*)&X[(size_t)gm * K + k0 + kq];
      As[kq + 0][row] = v.x; As[kq + 1][row] = v.y;
      As[kq + 2][row] = v.z; As[kq + 3][row] = v.w;
    }
#pragma unroll
    for (int i = 0; i < nB4; ++i) {
      int f = tid + i * 256;
      int kk = f / (BN / 4);
      int nq = (f % (BN / 4)) * 4;
      *(float4*)&Bs[kk][nq] = *(const float4*)&W[(size_t)(k0 + kk) * N + bc + nq];
    }
    __syncthreads();
#pragma unroll
    for (int kk = 0; kk < BK; ++kk) {
      float ar[2][4], brg[JH][4];
      *(float4*)&ar[0][0] = *(const float4*)&As[kk][trow * 4];
      *(float4*)&ar[1][0] = *(const float4*)&As[kk][trow * 4 + HM];
      if constexpr (JH == 2) {
        *(float4*)&brg[0][0] = *(const float4*)&Bs[kk][tcol * 4];
        *(float4*)&brg[1][0] = *(const float4*)&Bs[kk][tcol * 4 + HN];
      } else {
        *(float4*)&brg[0][0] = *(const float4*)&Bs[kk][tcol * 4];
      }
#pragma unroll
      for (int ih = 0; ih < 2; ++ih)
#pragma unroll
        for (int jh = 0; jh < JH; ++jh)
#pragma unroll
          for (int i = 0; i < 4; ++i)
#pragma unroll
            for (int j = 0; j < 4; ++j)
              acc[ih][jh][i][j] += ar[ih][i] * brg[jh][j];
    }
    __syncthreads();
  }
#pragma unroll
  for (int ih = 0; ih < 2; ++ih)
#pragma unroll
    for (int i = 0; i < 4; ++i) {
      int gm = br + ih * HM + trow * 4 + i;
      if (gm >= M) continue;
#pragma unroll
      for (int jh = 0; jh < JH; ++jh) {
        float4 o = make_float4(acc[ih][jh][i][0], acc[ih][jh][i][1],
                               acc[ih][jh][i][2], acc[ih][jh][i][3]);
        int gn = bc + (JH == 2 ? jh * HN : 0) + tcol * 4;
        *(float4*)&Y[(size_t)gm * N + gn] = o;
      }
    }
}

// ------------------------------------------------- per-node alpha_s/alpha_d
template <int H, int C>
__global__ void alpha_kernel(const float* __restrict__ h,
                             const float* __restrict__ a_s,
                             const float* __restrict__ a_d,
                             float* __restrict__ out_s,
                             float* __restrict__ out_d, int N) {
  constexpr int HC = H * C;
  constexpr int PER = HC / 64;
  constexpr int SEG = C / PER;
  int lane = threadIdx.x & 63;
  int node = (blockIdx.x * blockDim.x + threadIdx.x) >> 6;
  if (node >= N) return;
  int cbase = lane * PER;
  const float* row = h + (size_t)node * HC + cbase;
  float ss, dd;
  if constexpr (PER == 4) {
    float4 v = *(const float4*)row;
    float4 s4 = *(const float4*)(a_s + cbase);
    float4 d4 = *(const float4*)(a_d + cbase);
    ss = v.x * s4.x + v.y * s4.y + v.z * s4.z + v.w * s4.w;
    dd = v.x * d4.x + v.y * d4.y + v.z * d4.z + v.w * d4.w;
  } else {
    float v = row[0];
    ss = v * a_s[cbase];
    dd = v * a_d[cbase];
  }
#pragma unroll
  for (int off = SEG >> 1; off >= 1; off >>= 1) {
    ss += __shfl_xor(ss, off, 64);
    dd += __shfl_xor(dd, off, 64);
  }
  if ((lane % SEG) == 0) {
    int head = lane / SEG;
    out_s[(size_t)node * H + head] = ss;
    out_d[(size_t)node * H + head] = dd;
  }
}

// ------------------------------- segment softmax + mean-aggregate + bias(+relu)
// One wave per dst node. No max-pass (|e| small; softmax identical).
// deg<=64 fast path: lane-parallel edge weights, register-resident, shfl bcast.
template <int H, int C, bool RELU>
__global__ void aggregate_kernel(const float* __restrict__ h,
                                 const float* __restrict__ as_,
                                 const float* __restrict__ ad_,
                                 const int* __restrict__ row_ptr,
                                 const int* __restrict__ col_src,
                                 const float* __restrict__ bias,
                                 float* __restrict__ out, int N) {
  constexpr int HC = H * C;
  constexpr int PER = HC / 64;
  int lane = threadIdx.x & 63;
  int node = (blockIdx.x * blockDim.x + threadIdx.x) >> 6;
  if (node >= N) return;
  int beg = row_ptr[node], end = row_ptr[node + 1];
  int deg = end - beg;
  float adv[H];
#pragma unroll
  for (int hh = 0; hh < H; ++hh) adv[hh] = ad_[(size_t)node * H + hh];
  int myhead = (lane * PER) / C;
  float facc[PER] = {};

  if (deg <= 64) {
    // lane-parallel weights
    float p[H];
#pragma unroll
    for (int hh = 0; hh < H; ++hh) p[hh] = 0.f;
    int sreg = 0;
    if (lane < deg) {
      sreg = col_src[beg + lane];
#pragma unroll
      for (int hh = 0; hh < H; ++hh) {
        float e = as_[(size_t)sreg * H + hh] + adv[hh];
        e = (e > 0.f) ? e : NEG_SLOPE * e;
        p[hh] = __expf(e);
      }
    }
    float dn[H];
#pragma unroll
    for (int hh = 0; hh < H; ++hh) {
      dn[hh] = p[hh];
#pragma unroll
      for (int off = 32; off >= 1; off >>= 1)
        dn[hh] += __shfl_xor(dn[hh], off, 64);
    }
    float invdn;
    if constexpr (H == 4) {
      invdn = 1.f / (myhead == 0 ? dn[0] : myhead == 1 ? dn[1] : myhead == 2 ? dn[2] : dn[3]);
    } else {
      invdn = 1.f / dn[0];
    }
    for (int i = 0; i < deg; ++i) {
      int s = __shfl(sreg, i, 64);
      float w;
      if constexpr (H == 4) {
        float w0 = __shfl(p[0], i, 64), w1 = __shfl(p[1], i, 64);
        float w2 = __shfl(p[2], i, 64), w3 = __shfl(p[3], i, 64);
        w = myhead == 0 ? w0 : myhead == 1 ? w1 : myhead == 2 ? w2 : w3;
      } else {
        w = __shfl(p[0], i, 64);
      }
      w *= invdn;
      const float* hrow = h + (size_t)s * HC + lane * PER;
      if constexpr (PER == 4) {
        float4 v = *(const float4*)hrow;
        facc[0] += v.x * w; facc[1] += v.y * w;
        facc[2] += v.z * w; facc[3] += v.w * w;
      } else {
        facc[0] += hrow[0] * w;
      }
    }
  } else {
    // generic slow path (deg > 64): two passes, no max
    float dn[H];
#pragma unroll
    for (int hh = 0; hh < H; ++hh) dn[hh] = 0.f;
    for (int i = beg + lane; i < end; i += 64) {
      int s = col_src[i];
#pragma unroll
      for (int hh = 0; hh < H; ++hh) {
        float e = as_[(size_t)s * H + hh] + adv[hh];
        e = (e > 0.f) ? e : NEG_SLOPE * e;
        dn[hh] += __expf(e);
      }
    }
#pragma unroll
    for (int hh = 0; hh < H; ++hh)
#pragma unroll
      for (int off = 32; off >= 1; off >>= 1)
        dn[hh] += __shfl_xor(dn[hh], off, 64);
    float adm, invdn;
    if constexpr (H == 4) {
      adm = myhead == 0 ? adv[0] : myhead == 1 ? adv[1] : myhead == 2 ? adv[2] : adv[3];
      invdn = 1.f / (myhead == 0 ? dn[0] : myhead == 1 ? dn[1] : myhead == 2 ? dn[2] : dn[3]);
    } else {
      adm = adv[0]; invdn = 1.f / dn[0];
    }
    for (int i = beg; i < end; ++i) {
      int s = col_src[i];
      float e = as_[(size_t)s * H + myhead] + adm;
      e = (e > 0.f) ? e : NEG_SLOPE * e;
      float w = __expf(e) * invdn;
      const float* hrow = h + (size_t)s * HC + lane * PER;
      if constexpr (PER == 4) {
        float4 v = *(const float4*)hrow;
        facc[0] += v.x * w; facc[1] += v.y * w;
        facc[2] += v.z * w; facc[3] += v.w * w;
      } else {
        facc[0] += hrow[0] * w;
      }
    }
  }

  float inv_deg = 1.0f / (float)deg;
  float* orow = out + (size_t)node * HC + lane * PER;
#pragma unroll
  for (int p = 0; p < PER; ++p) {
    float v = facc[p] * inv_deg + bias[lane * PER + p];
    if (RELU) v = fmaxf(v, 0.f);
    orow[p] = v;
  }
}

// ---------------------------------------------------------------- launcher
extern "C" void kernel_launch(void* const* d_in, const int* in_sizes, int n_in,
                              void* d_out, int out_size, void* d_ws, size_t ws_size,
                              hipStream_t stream) {
  const float* x   = (const float*)d_in[0];
  const int*   ei  = (const int*)d_in[1];
  const float* W0  = (const float*)d_in[2];
  const float* a0s = (const float*)d_in[3];
  const float* a0d = (const float*)d_in[4];
  const float* b0  = (const float*)d_in[5];
  const float* W1  = (const float*)d_in[6];
  const float* a1s = (const float*)d_in[7];
  const float* a1d = (const float*)d_in[8];
  const float* b1  = (const float*)d_in[9];
  const float* W2  = (const float*)d_in[10];
  const float* a2s = (const float*)d_in[11];
  const float* a2d = (const float*)d_in[12];
  const float* b2  = (const float*)d_in[13];

  const int IN = 256;
  const int N = in_sizes[0] / IN;       // 50000
  const int E = in_sizes[1] / 2;        // 600000
  const int Etot = E + N;

  char* ws = (char*)d_ws;
  size_t off = 0;
  auto alloc = [&](size_t bytes) {
    void* p = ws + off;
    off += (bytes + 255) & ~(size_t)255;
    return p;
  };
  float* A       = (float*)alloc((size_t)N * 256 * 4);  // GEMM output / h_lin
  float* Bbuf    = (float*)alloc((size_t)N * 256 * 4);  // aggregated output
  float* as_buf  = (float*)alloc((size_t)N * 4 * 4);
  float* ad_buf  = (float*)alloc((size_t)N * 4 * 4);
  int*   row_ptr = (int*)alloc((size_t)(N + 1) * 4);
  int*   cursor  = (int*)alloc((size_t)N * 4);
  int*   cnt     = (int*)alloc((size_t)N * 4);
  int*   col_src = (int*)alloc((size_t)Etot * 4);

  // ---- CSR build ----
  zero_int_kernel<<<(N + 255) / 256, 256, 0, stream>>>(cnt, N);
  count_kernel<<<(Etot + 255) / 256, 256, 0, stream>>>(ei, E, N, cnt);
  scan_kernel<<<1, 1024, 0, stream>>>(cnt, row_ptr, cursor, N);
  fill_kernel<<<(Etot + 255) / 256, 256, 0, stream>>>(ei, E, N, cursor, col_src);

  dim3 g0(256 / 128, (N + 127) / 128);  // 2 x 391
  dim3 g2(64 / 64, (N + 127) / 128);    // 1 x 391
  int node_blocks = (N + 3) / 4;        // 4 waves/block, 1 wave/node

  // ---- layer 0 ----
  sgemm_kernel<128, 128><<<g0, 256, 0, stream>>>(x, W0, A, N, 256, 256);
  alpha_kernel<4, 64><<<node_blocks, 256, 0, stream>>>(A, a0s, a0d, as_buf, ad_buf, N);
  aggregate_kernel<4, 64, true><<<node_blocks, 256, 0, stream>>>(
      A, as_buf, ad_buf, row_ptr, col_src, b0, Bbuf, N);

  // ---- layer 1 ----
  sgemm_kernel<128, 128><<<g0, 256, 0, stream>>>(Bbuf, W1, A, N, 256, 256);
  alpha_kernel<4, 64><<<node_blocks, 256, 0, stream>>>(A, a1s, a1d, as_buf, ad_buf, N);
  aggregate_kernel<4, 64, true><<<node_blocks, 256, 0, stream>>>(
      A, as_buf, ad_buf, row_ptr, col_src, b1, Bbuf, N);

  // ---- layer 2 ----
  sgemm_kernel<128, 64><<<g2, 256, 0, stream>>>(Bbuf, W2, A, N, 64, 256);
  alpha_kernel<1, 64><<<node_blocks, 256, 0, stream>>>(A, a2s, a2d, as_buf, ad_buf, N);
  aggregate_kernel<1, 64, false><<<node_blocks, 256, 0, stream>>>(
      A, as_buf, ad_buf, row_ptr, col_src, b2, (float*)d_out, N);
}